// Round 4
// baseline (850.301 us; speedup 1.0000x reference)
//
#include <hip/hip_runtime.h>
#include <math.h>

#define NROWS 16384   // B*T
#define HALF_ROWS 8192
#define INCH  512
#define CH    2048
#define DD    256
#define MM    1024

typedef unsigned short u16;
typedef short short8 __attribute__((ext_vector_type(8)));
typedef float f32x4 __attribute__((ext_vector_type(4)));

__device__ __forceinline__ u16 f2bf(float f) {
  unsigned u = __float_as_uint(f);
  return (u16)((u + 0x7fffu + ((u >> 16) & 1u)) >> 16);
}
__device__ __forceinline__ float bf2f(u16 h) {
  return __uint_as_float(((unsigned)h) << 16);
}
__device__ __forceinline__ void gload16(const u16* g, u16* lds) {
  __builtin_amdgcn_global_load_lds((const __attribute__((address_space(1))) void*)g,
                                   (__attribute__((address_space(3))) void*)lds, 16, 0, 0);
}

// ---------------------------------------------------------------------------
// split: fp32 -> bf16 hi/lo pair (per half: 8192x512)
// ---------------------------------------------------------------------------
__global__ __launch_bounds__(256) void k_split_x(const float* __restrict__ x,
                                                 u16* __restrict__ xh, u16* __restrict__ xl) {
  const size_t i = ((size_t)blockIdx.x * 256 + threadIdx.x) * 8;
  float4 a = *(const float4*)(x + i);
  float4 b = *(const float4*)(x + i + 4);
  float v[8] = {a.x, a.y, a.z, a.w, b.x, b.y, b.z, b.w};
  unsigned hw[4], lw[4];
#pragma unroll
  for (int p = 0; p < 4; ++p) {
    u16 h0 = f2bf(v[2*p]), h1 = f2bf(v[2*p+1]);
    u16 l0 = f2bf(v[2*p] - bf2f(h0)), l1 = f2bf(v[2*p+1] - bf2f(h1));
    hw[p] = (unsigned)h0 | ((unsigned)h1 << 16);
    lw[p] = (unsigned)l0 | ((unsigned)l1 << 16);
  }
  *(uint4*)(xh + i) = make_uint4(hw[0], hw[1], hw[2], hw[3]);
  *(uint4*)(xl + i) = make_uint4(lw[0], lw[1], lw[2], lw[3]);
}

// src [R][C] fp32  ->  dh/dl [C][R] bf16 hi/lo   (transpose + split)
__global__ __launch_bounds__(256) void k_split_wT(const float* __restrict__ src,
                                                  u16* __restrict__ dh, u16* __restrict__ dl,
                                                  int R, int C) {
  __shared__ float t[32][33];
  const int tx = threadIdx.x & 31, ty = threadIdx.x >> 5;
  const int c0 = blockIdx.x * 32, r0 = blockIdx.y * 32;
#pragma unroll
  for (int i = 0; i < 4; ++i)
    t[ty + i * 8][tx] = src[(size_t)(r0 + ty + i * 8) * C + c0 + tx];
  __syncthreads();
#pragma unroll
  for (int i = 0; i < 4; ++i) {
    float v = t[tx][ty + i * 8];
    size_t o = (size_t)(c0 + ty + i * 8) * R + r0 + tx;
    u16 h = f2bf(v);
    dh[o] = h;
    dl[o] = f2bf(v - bf2f(h));
  }
}

// ---------------------------------------------------------------------------
// K1: H(split) = X @ W1 via split-bf16 MFMA. 128x128 tile, BK=32, 4 waves.
// ---------------------------------------------------------------------------
__global__ __launch_bounds__(256) void k_gemm1(const u16* __restrict__ Xh, const u16* __restrict__ Xl,
                                               const u16* __restrict__ W1ht, const u16* __restrict__ W1lt,
                                               u16* __restrict__ Hh, u16* __restrict__ Hl) {
  __shared__ u16 sm[2][2048 * 8];
  const int tid = threadIdx.x;
  const int lane = tid & 63, w = tid >> 6;
  const int wr = w >> 1, wc = w & 1;
  const int gm = blockIdx.y * 128, n0 = blockIdx.x * 128;

  const u16* srcbase = (w == 0) ? Xh : (w == 1) ? Xl : (w == 2) ? W1ht : W1lt;
  const int rowbase = (w < 2) ? gm : n0;

  f32x4 acc[4][4];
#pragma unroll
  for (int i = 0; i < 4; ++i)
#pragma unroll
    for (int j = 0; j < 4; ++j) acc[i][j] = (f32x4){0.f, 0.f, 0.f, 0.f};

  auto STAGE = [&](int buf, int kt) {
#pragma unroll
    for (int t = 0; t < 8; ++t) {
      int c = t * 64 + lane;
      int kc = c >> 7, r = c & 127;
      const u16* g = srcbase + ((size_t)(rowbase + r) << 9) + (kt << 5) + (kc << 3);
      gload16(g, &sm[buf][(w * 512 + t * 64) * 8]);
    }
  };

  STAGE(0, 0);
  for (int kt = 0; kt < 16; ++kt) {
    __syncthreads();
    if (kt + 1 < 16) STAGE((kt + 1) & 1, kt + 1);
    const u16* base = sm[kt & 1];
    const int lr = lane & 15, kc = lane >> 4;
    short8 ah[4], al[4], bh[4], bl[4];
#pragma unroll
    for (int i = 0; i < 4; ++i) {
      ah[i] = *(const short8*)(base + (kc * 128 + wr * 64 + i * 16 + lr) * 8);
      al[i] = *(const short8*)(base + (512 + kc * 128 + wr * 64 + i * 16 + lr) * 8);
      bh[i] = *(const short8*)(base + (1024 + kc * 128 + wc * 64 + i * 16 + lr) * 8);
      bl[i] = *(const short8*)(base + (1536 + kc * 128 + wc * 64 + i * 16 + lr) * 8);
    }
#pragma unroll
    for (int i = 0; i < 4; ++i)
#pragma unroll
      for (int j = 0; j < 4; ++j) {
        acc[i][j] = __builtin_amdgcn_mfma_f32_16x16x32_bf16(ah[i], bh[j], acc[i][j], 0, 0, 0);
        acc[i][j] = __builtin_amdgcn_mfma_f32_16x16x32_bf16(ah[i], bl[j], acc[i][j], 0, 0, 0);
        acc[i][j] = __builtin_amdgcn_mfma_f32_16x16x32_bf16(al[i], bh[j], acc[i][j], 0, 0, 0);
      }
  }

  const int rr = (lane >> 4) << 2, cc = lane & 15;
#pragma unroll
  for (int i = 0; i < 4; ++i)
#pragma unroll
    for (int j = 0; j < 4; ++j) {
#pragma unroll
      for (int reg = 0; reg < 4; ++reg) {
        size_t o = (size_t)(gm + wr * 64 + i * 16 + rr + reg) * CH + (n0 + wc * 64 + j * 16 + cc);
        float v = acc[i][j][reg];
        u16 h = f2bf(v);
        Hh[o] = h;
        Hl[o] = f2bf(v - bf2f(h));
      }
    }
}

// ---------------------------------------------------------------------------
// K2: in-place LayerNorm + ReLU on split H. One block per row.
// ---------------------------------------------------------------------------
__global__ __launch_bounds__(256) void k_ln(u16* __restrict__ Hh, u16* __restrict__ Hl,
                                            const float* __restrict__ g, const float* __restrict__ b) {
  __shared__ float red[8];
  const int row = blockIdx.x;
  const int tid = threadIdx.x;
  uint4* hp = (uint4*)(Hh + (size_t)row * CH);
  uint4* lp = (uint4*)(Hl + (size_t)row * CH);
  uint4 hh = hp[tid], ll = lp[tid];
  float f[8];
  {
    unsigned hw[4] = {hh.x, hh.y, hh.z, hh.w};
    unsigned lw[4] = {ll.x, ll.y, ll.z, ll.w};
#pragma unroll
    for (int p = 0; p < 4; ++p) {
      f[2*p]   = bf2f((u16)(hw[p] & 0xffffu)) + bf2f((u16)(lw[p] & 0xffffu));
      f[2*p+1] = bf2f((u16)(hw[p] >> 16))     + bf2f((u16)(lw[p] >> 16));
    }
  }
  float s = 0.f, ss = 0.f;
#pragma unroll
  for (int j = 0; j < 8; ++j) { s += f[j]; ss += f[j] * f[j]; }
#pragma unroll
  for (int m = 32; m; m >>= 1) { s += __shfl_xor(s, m); ss += __shfl_xor(ss, m); }
  if ((tid & 63) == 0) { red[(tid >> 6) * 2] = s; red[(tid >> 6) * 2 + 1] = ss; }
  __syncthreads();
  s  = red[0] + red[2] + red[4] + red[6];
  ss = red[1] + red[3] + red[5] + red[7];
  const float mu  = s * (1.f / CH);
  const float var = ss * (1.f / CH) - mu * mu;
  const float rinv = 1.f / sqrtf(var + 1e-5f);
  float4 g0 = ((const float4*)g)[tid * 2], g1 = ((const float4*)g)[tid * 2 + 1];
  float4 b0 = ((const float4*)b)[tid * 2], b1 = ((const float4*)b)[tid * 2 + 1];
  float gg[8] = {g0.x, g0.y, g0.z, g0.w, g1.x, g1.y, g1.z, g1.w};
  float bb[8] = {b0.x, b0.y, b0.z, b0.w, b1.x, b1.y, b1.z, b1.w};
  unsigned hw[4], lw[4];
#pragma unroll
  for (int p = 0; p < 4; ++p) {
    float y0 = fmaxf((f[2*p]   - mu) * rinv * gg[2*p]   + bb[2*p],   0.f);
    float y1 = fmaxf((f[2*p+1] - mu) * rinv * gg[2*p+1] + bb[2*p+1], 0.f);
    u16 h0 = f2bf(y0), h1 = f2bf(y1);
    u16 l0 = f2bf(y0 - bf2f(h0)), l1 = f2bf(y1 - bf2f(h1));
    hw[p] = (unsigned)h0 | ((unsigned)h1 << 16);
    lw[p] = (unsigned)l0 | ((unsigned)l1 << 16);
  }
  hp[tid] = make_uint4(hw[0], hw[1], hw[2], hw[3]);
  lp[tid] = make_uint4(lw[0], lw[1], lw[2], lw[3]);
}

// ---------------------------------------------------------------------------
// K3: PART[kz] = H @ W2 (K-chunk kz). Split-bf16 MFMA, split-K=4.
// BM=64, BN=128, BK=32; 4 waves as 2x2 (wave tile 32 rows x 64 cols).
// LDS chunks/buf: Ah 0(256), Al 256, Bh 512(512), Bl 1024 -> 1536*16B = 24KB
// ---------------------------------------------------------------------------
__global__ __launch_bounds__(256) void k_gemm2(const u16* __restrict__ Hh, const u16* __restrict__ Hl,
                                               const u16* __restrict__ W2ht, const u16* __restrict__ W2lt,
                                               float* __restrict__ PART) {
  __shared__ u16 sm[2][1536 * 8];
  const int tid = threadIdx.x;
  const int lane = tid & 63, w = tid >> 6;
  const int wr = w >> 1, wc = w & 1;
  const int gm = blockIdx.y * 64, n0 = blockIdx.x * 128;
  const int kbase = blockIdx.z * 512;

  f32x4 acc[2][4];
#pragma unroll
  for (int i = 0; i < 2; ++i)
#pragma unroll
    for (int j = 0; j < 4; ++j) acc[i][j] = (f32x4){0.f, 0.f, 0.f, 0.f};

  auto STAGE = [&](int buf, int kt) {
#pragma unroll
    for (int t = 0; t < 6; ++t) {
      const int c = w * 384 + t * 64 + lane;
      const u16* src;
      int rowbase, kc, r;
      if (c < 512) {
        const int wi = c & 255;
        kc = wi >> 6; r = wi & 63;
        src = (c < 256) ? Hh : Hl;
        rowbase = gm;
      } else {
        const int wi = (c - 512) & 511;
        kc = wi >> 7; r = wi & 127;
        src = (c < 1024) ? W2ht : W2lt;
        rowbase = n0;
      }
      const u16* g = src + ((size_t)(rowbase + r) << 11) + kbase + (kt << 5) + (kc << 3);
      gload16(g, &sm[buf][c * 8]);
    }
  };

  STAGE(0, 0);
  for (int kt = 0; kt < 16; ++kt) {
    __syncthreads();
    if (kt + 1 < 16) STAGE((kt + 1) & 1, kt + 1);
    const u16* base = sm[kt & 1];
    const int lr = lane & 15, kc = lane >> 4;
    short8 ah[2], al[2], bh[4], bl[4];
#pragma unroll
    for (int i = 0; i < 2; ++i) {
      ah[i] = *(const short8*)(base + (kc * 64 + wr * 32 + i * 16 + lr) * 8);
      al[i] = *(const short8*)(base + (256 + kc * 64 + wr * 32 + i * 16 + lr) * 8);
    }
#pragma unroll
    for (int j = 0; j < 4; ++j) {
      bh[j] = *(const short8*)(base + (512 + kc * 128 + wc * 64 + j * 16 + lr) * 8);
      bl[j] = *(const short8*)(base + (1024 + kc * 128 + wc * 64 + j * 16 + lr) * 8);
    }
#pragma unroll
    for (int i = 0; i < 2; ++i)
#pragma unroll
      for (int j = 0; j < 4; ++j) {
        acc[i][j] = __builtin_amdgcn_mfma_f32_16x16x32_bf16(ah[i], bh[j], acc[i][j], 0, 0, 0);
        acc[i][j] = __builtin_amdgcn_mfma_f32_16x16x32_bf16(ah[i], bl[j], acc[i][j], 0, 0, 0);
        acc[i][j] = __builtin_amdgcn_mfma_f32_16x16x32_bf16(al[i], bh[j], acc[i][j], 0, 0, 0);
      }
  }

  float* pout = PART + (size_t)blockIdx.z * HALF_ROWS * DD;
  const int rr = (lane >> 4) << 2, cc = lane & 15;
#pragma unroll
  for (int i = 0; i < 2; ++i)
#pragma unroll
    for (int j = 0; j < 4; ++j)
#pragma unroll
      for (int reg = 0; reg < 4; ++reg) {
        const int row = gm + wr * 32 + i * 16 + rr + reg;
        const int col = n0 + wc * 64 + j * 16 + cc;
        pout[(size_t)row * DD + col] = acc[i][j][reg];
      }
}

// ---------------------------------------------------------------------------
// K3b: finish = sum 4 partials + bias -> z; per-head LSE -> p; outputs:
// Z (fp32), EXh/EXl (split bf16 of exp(p)), SELF = sum ex*p. Wave per row.
// ---------------------------------------------------------------------------
__global__ __launch_bounds__(256) void k_finish(const float* __restrict__ PART,
                                                const float* __restrict__ b2,
                                                float* __restrict__ Z,
                                                u16* __restrict__ EXh, u16* __restrict__ EXl,
                                                float* __restrict__ SELF) {
  const int tid = threadIdx.x;
  const int lane = tid & 63;
  const int row = blockIdx.x * 4 + (tid >> 6);
  const size_t off = (size_t)row * DD + lane * 4;

  float4 z4 = *(const float4*)&PART[off];
#pragma unroll
  for (int s = 1; s < 4; ++s) {
    float4 p4 = *(const float4*)&PART[(size_t)s * HALF_ROWS * DD + off];
    z4.x += p4.x; z4.y += p4.y; z4.z += p4.z; z4.w += p4.w;
  }
  float4 bias = *(const float4*)&b2[lane * 4];
  z4.x += bias.x; z4.y += bias.y; z4.z += bias.z; z4.w += bias.w;

  // per-head LSE: 16-lane group = one 64-col head
  float mx = fmaxf(fmaxf(z4.x, z4.y), fmaxf(z4.z, z4.w));
#pragma unroll
  for (int m = 1; m <= 8; m <<= 1) mx = fmaxf(mx, __shfl_xor(mx, m));
  float se = expf(z4.x - mx) + expf(z4.y - mx) + expf(z4.z - mx) + expf(z4.w - mx);
#pragma unroll
  for (int m = 1; m <= 8; m <<= 1) se += __shfl_xor(se, m);
  const float lse = mx + logf(se);

  float p[4] = {z4.x - lse, z4.y - lse, z4.z - lse, z4.w - lse};
  float e[4] = {expf(p[0]), expf(p[1]), expf(p[2]), expf(p[3])};
  float self = e[0]*p[0] + e[1]*p[1] + e[2]*p[2] + e[3]*p[3];
#pragma unroll
  for (int m = 32; m; m >>= 1) self += __shfl_xor(self, m);
  if (lane == 0) SELF[row] = self;

  *(float4*)&Z[off] = z4;
  u16 h[4], l[4];
#pragma unroll
  for (int q = 0; q < 4; ++q) {
    h[q] = f2bf(e[q]);
    l[q] = f2bf(e[q] - bf2f(h[q]));
  }
  *(uint2*)&EXh[off] = make_uint2((unsigned)h[0] | ((unsigned)h[1] << 16),
                                  (unsigned)h[2] | ((unsigned)h[3] << 16));
  *(uint2*)&EXl[off] = make_uint2((unsigned)l[0] | ((unsigned)l[1] << 16),
                                  (unsigned)l[2] | ((unsigned)l[3] << 16));
}

// ---------------------------------------------------------------------------
// K4b: logE = log(emb), 3-split bf16 (hi/mid/lo), layout [1024][256]
// ---------------------------------------------------------------------------
__global__ __launch_bounds__(256) void k_prep_le(const float* __restrict__ E,
                                                 u16* __restrict__ LEh, u16* __restrict__ LEm,
                                                 u16* __restrict__ LEl) {
  const size_t i = ((size_t)blockIdx.x * 256 + threadIdx.x) * 4;
  float4 v4 = *(const float4*)&E[i];
  float v[4] = {logf(v4.x), logf(v4.y), logf(v4.z), logf(v4.w)};
  u16 h[4], m_[4], l[4];
#pragma unroll
  for (int e = 0; e < 4; ++e) {
    h[e] = f2bf(v[e]);
    float r1 = v[e] - bf2f(h[e]);
    m_[e] = f2bf(r1);
    float r2 = r1 - bf2f(m_[e]);
    l[e] = f2bf(r2);
  }
  *(uint2*)&LEh[i] = make_uint2((unsigned)h[0] | ((unsigned)h[1] << 16), (unsigned)h[2] | ((unsigned)h[3] << 16));
  *(uint2*)&LEm[i] = make_uint2((unsigned)m_[0] | ((unsigned)m_[1] << 16), (unsigned)m_[2] | ((unsigned)m_[3] << 16));
  *(uint2*)&LEl[i] = make_uint2((unsigned)l[0] | ((unsigned)l[1] << 16), (unsigned)l[2] | ((unsigned)l[3] << 16));
}

// ---------------------------------------------------------------------------
// K5: DOTS[N,1024] = EX @ LE^T via 5-term split MFMA (ex 2-split x logE 3-split)
// ---------------------------------------------------------------------------
__global__ __launch_bounds__(256) void k_dots(const u16* __restrict__ EXh, const u16* __restrict__ EXl,
                                              const u16* __restrict__ LEh, const u16* __restrict__ LEm,
                                              const u16* __restrict__ LEl,
                                              float* __restrict__ DOTS) {
  __shared__ u16 sm[2560 * 8];
  const int tid = threadIdx.x;
  const int lane = tid & 63, w = tid >> 6;
  const int wr = w >> 1, wc = w & 1;
  const int gm = blockIdx.y * 128, m0 = blockIdx.x * 128;

  f32x4 acc[4][4];
#pragma unroll
  for (int i = 0; i < 4; ++i)
#pragma unroll
    for (int j = 0; j < 4; ++j) acc[i][j] = (f32x4){0.f, 0.f, 0.f, 0.f};

  for (int kt = 0; kt < 8; ++kt) {
    __syncthreads();
#pragma unroll
    for (int t = 0; t < 10; ++t) {
      const int c = w * 640 + t * 64 + lane;
      const int slab = c >> 9;
      const int within = c & 511;
      const int kc = within >> 7, r = within & 127;
      const u16* src = (slab == 0) ? EXh : (slab == 1) ? EXl :
                       (slab == 2) ? LEh : (slab == 3) ? LEm : LEl;
      const int rowbase = (slab < 2) ? gm : m0;
      const u16* g = src + ((size_t)(rowbase + r) << 8) + (kt << 5) + (kc << 3);
      gload16(g, &sm[(w * 640 + t * 64) * 8]);
    }
    __syncthreads();
    const int lr = lane & 15, kc2 = lane >> 4;
    short8 eh[4], el[4], bh[4], bm[4], bl[4];
#pragma unroll
    for (int i = 0; i < 4; ++i) {
      eh[i] = *(const short8*)(sm + ((kc2 * 128 + wr * 64 + i * 16 + lr)) * 8);
      el[i] = *(const short8*)(sm + ((512 + kc2 * 128 + wr * 64 + i * 16 + lr)) * 8);
      bh[i] = *(const short8*)(sm + ((1024 + kc2 * 128 + wc * 64 + i * 16 + lr)) * 8);
      bm[i] = *(const short8*)(sm + ((1536 + kc2 * 128 + wc * 64 + i * 16 + lr)) * 8);
      bl[i] = *(const short8*)(sm + ((2048 + kc2 * 128 + wc * 64 + i * 16 + lr)) * 8);
    }
#pragma unroll
    for (int i = 0; i < 4; ++i)
#pragma unroll
      for (int j = 0; j < 4; ++j) {
        acc[i][j] = __builtin_amdgcn_mfma_f32_16x16x32_bf16(eh[i], bh[j], acc[i][j], 0, 0, 0);
        acc[i][j] = __builtin_amdgcn_mfma_f32_16x16x32_bf16(eh[i], bm[j], acc[i][j], 0, 0, 0);
        acc[i][j] = __builtin_amdgcn_mfma_f32_16x16x32_bf16(eh[i], bl[j], acc[i][j], 0, 0, 0);
        acc[i][j] = __builtin_amdgcn_mfma_f32_16x16x32_bf16(el[i], bh[j], acc[i][j], 0, 0, 0);
        acc[i][j] = __builtin_amdgcn_mfma_f32_16x16x32_bf16(el[i], bm[j], acc[i][j], 0, 0, 0);
      }
  }

  const int rr = (lane >> 4) << 2, cc = lane & 15;
#pragma unroll
  for (int i = 0; i < 4; ++i)
#pragma unroll
    for (int j = 0; j < 4; ++j)
#pragma unroll
      for (int reg = 0; reg < 4; ++reg) {
        const int row = gm + wr * 64 + i * 16 + rr + reg;
        const int col = m0 + wc * 64 + j * 16 + cc;
        DOTS[((size_t)row << 10) + col] = acc[i][j][reg];
      }
}

// ---------------------------------------------------------------------------
// K6: per row: argmax(dots), KL = self - max, fused gather Q. Wave per row.
// ---------------------------------------------------------------------------
__global__ __launch_bounds__(256) void k_scan(const float* __restrict__ DOTS,
                                              const float* __restrict__ SELF,
                                              const float* __restrict__ E,
                                              float* __restrict__ Q,
                                              float* __restrict__ KL) {
  const int tid = threadIdx.x;
  const int lane = tid & 63;
  const int row = blockIdx.x * 4 + (tid >> 6);

  float bv = -1e30f;
  int bi = 0x7fffffff;
#pragma unroll
  for (int q = 0; q < 4; ++q) {
    const int c0 = q * 256 + lane * 4;
    float4 v = *(const float4*)&DOTS[((size_t)row << 10) + c0];
    if (v.x > bv) { bv = v.x; bi = c0; }
    if (v.y > bv) { bv = v.y; bi = c0 + 1; }
    if (v.z > bv) { bv = v.z; bi = c0 + 2; }
    if (v.w > bv) { bv = v.w; bi = c0 + 3; }
  }
#pragma unroll
  for (int m = 32; m; m >>= 1) {
    float ov = __shfl_xor(bv, m);
    int   oi = __shfl_xor(bi, m);
    if (ov > bv || (ov == bv && oi < bi)) { bv = ov; bi = oi; }
  }
  if (lane == 0) KL[row] = SELF[row] - bv;
  float4 e4 = *(const float4*)&E[((size_t)bi << 8) + lane * 4];
  *(float4*)&Q[((size_t)row << 8) + lane * 4] = e4;
}

// ---------------------------------------------------------------------------
// K7: loss = 0.25/B * sum_n kl[n]*mask[n]
// ---------------------------------------------------------------------------
__global__ __launch_bounds__(256) void k_loss(const float* __restrict__ KL,
                                              const float* __restrict__ MASK,
                                              float* __restrict__ out) {
  __shared__ float red[4];
  const int tid = threadIdx.x;
  float s = 0.f;
  for (int i = tid; i < NROWS; i += 256) s += KL[i] * MASK[i];
#pragma unroll
  for (int m = 32; m; m >>= 1) s += __shfl_xor(s, m);
  if ((tid & 63) == 0) red[tid >> 6] = s;
  __syncthreads();
  if (tid == 0) out[0] = (red[0] + red[1] + red[2] + red[3]) * (0.25f / 16.f);
}

// ---------------------------------------------------------------------------
extern "C" void kernel_launch(void* const* d_in, const int* in_sizes, int n_in,
                              void* d_out, int out_size, void* d_ws, size_t ws_size,
                              hipStream_t stream) {
  const float* x     = (const float*)d_in[0];
  const float* masks = (const float*)d_in[1];
  const float* W1    = (const float*)d_in[2];
  const float* ln_g  = (const float*)d_in[3];
  const float* ln_b  = (const float*)d_in[4];
  const float* W2    = (const float*)d_in[5];
  const float* b2    = (const float*)d_in[6];
  const float* emb   = (const float*)d_in[7];

  float* z_out = (float*)d_out;
  float* q_out = z_out + (size_t)NROWS * DD;
  float* loss_out = z_out + 2 * (size_t)NROWS * DD;

  char* ws = (char*)d_ws;
  u16*   Hh   = (u16*)(ws);                    //  33,554,432 (half: 8192x2048)
  u16*   Hl   = (u16*)(ws + 33554432);         //  33,554,432
  u16*   Xh   = (u16*)(ws + 67108864);         //   8,388,608 (half: 8192x512)
  u16*   Xl   = (u16*)(ws + 75497472);         //   8,388,608
  u16*   W1ht = (u16*)(ws + 83886080);         //   2,097,152
  u16*   W1lt = (u16*)(ws + 85983232);         //   2,097,152
  u16*   W2ht = (u16*)(ws + 88080384);         //   1,048,576
  u16*   W2lt = (u16*)(ws + 89128960);         //   1,048,576
  u16*   LEh  = (u16*)(ws + 90177536);         //     524,288
  u16*   LEm  = (u16*)(ws + 90701824);         //     524,288
  u16*   LEl  = (u16*)(ws + 91226112);         //     524,288
  float* KL   = (float*)(ws + 91750400);       //      65,536
  float* SELF = (float*)(ws + 91815936);       //      65,536
  u16*   EXh  = (u16*)(ws + 91881472);         //   8,388,608 (full: 16384x256)
  u16*   EXl  = (u16*)(ws + 100270080);        //   8,388,608
  float* PART = (float*)(ws + 108658688);      //  33,554,432 (4x8192x256 fp32)
                                               //  -> end 142,213,120
  float* DOTS = (float*)(ws);                  //  67,108,864 overlay (H dead)

  k_split_wT<<<dim3(64, 16), 256, 0, stream>>>(W1, W1ht, W1lt, INCH, CH);
  k_split_wT<<<dim3(8, 64), 256, 0, stream>>>(W2, W2ht, W2lt, CH, DD);
  k_prep_le<<<256, 256, 0, stream>>>(emb, LEh, LEm, LEl);

  for (int half = 0; half < 2; ++half) {
    const size_t xo = (size_t)half * HALF_ROWS * INCH;
    const size_t zo = (size_t)half * HALF_ROWS * DD;
    k_split_x<<<2048, 256, 0, stream>>>(x + xo, Xh, Xl);
    k_gemm1<<<dim3(16, 64), 256, 0, stream>>>(Xh, Xl, W1ht, W1lt, Hh, Hl);
    k_ln<<<HALF_ROWS, 256, 0, stream>>>(Hh, Hl, ln_g, ln_b);
    k_gemm2<<<dim3(2, 128, 4), 256, 0, stream>>>(Hh, Hl, W2ht, W2lt, PART);
    k_finish<<<HALF_ROWS / 4, 256, 0, stream>>>(PART, b2, z_out + zo,
                                                EXh + zo, EXl + zo, SELF + half * HALF_ROWS);
  }

  k_dots<<<dim3(8, 128), 256, 0, stream>>>(EXh, EXl, LEh, LEm, LEl, DOTS);
  k_scan<<<4096, 256, 0, stream>>>(DOTS, SELF, emb, q_out, KL);
  k_loss<<<1, 256, 0, stream>>>(KL, masks, loss_out);
}

// Round 5
// 375.694 us; speedup vs baseline: 2.2633x; 2.2633x over previous
//
#include <hip/hip_runtime.h>
#include <math.h>

#define NROWS 16384   // B*T
#define QROWS 4096
#define INCH  512
#define CH    2048
#define DD    256
#define MM    1024

typedef unsigned short u16;
typedef short short8 __attribute__((ext_vector_type(8)));
typedef float f32x4 __attribute__((ext_vector_type(4)));

__device__ __forceinline__ u16 f2bf(float f) {
  unsigned u = __float_as_uint(f);
  return (u16)((u + 0x7fffu + ((u >> 16) & 1u)) >> 16);
}
__device__ __forceinline__ float bf2f(u16 h) {
  return __uint_as_float(((unsigned)h) << 16);
}
__device__ __forceinline__ void gload16(const u16* g, u16* lds) {
  __builtin_amdgcn_global_load_lds((const __attribute__((address_space(1))) void*)g,
                                   (__attribute__((address_space(3))) void*)lds, 16, 0, 0);
}

// Coalesced-staging chunk mapping (16B chunks of 8 bf16 along K):
//   physical chunk PC(row,kc) = (row>>4)*64 + (row&15)*4 + (kc ^ ((row>>1)&3))
//   staging instr t, lane i: row = t*16 + (i>>2), k16 = (i&3) ^ ((i>>3)&3),
//                            LDS slot = t*64 + i  (linear in lane -> gload_lds OK)
//   -> 4 lanes read one contiguous 64B row segment (16 lines/instr, not 64)
//   read (MFMA frag, rowoff%16==0): chunk = (rowoff>>4)*64 + rI where
//   rI = (lane&15)*4 + ((lane>>4) ^ ((lane>>1)&3))  -> 2-way banks (free)

// ---------------------------------------------------------------------------
// split: fp32 -> bf16 hi/lo pair (quarter: 4096x512)
// ---------------------------------------------------------------------------
__global__ __launch_bounds__(256) void k_split_x(const float* __restrict__ x,
                                                 u16* __restrict__ xh, u16* __restrict__ xl) {
  const size_t i = ((size_t)blockIdx.x * 256 + threadIdx.x) * 8;
  float4 a = *(const float4*)(x + i);
  float4 b = *(const float4*)(x + i + 4);
  float v[8] = {a.x, a.y, a.z, a.w, b.x, b.y, b.z, b.w};
  unsigned hw[4], lw[4];
#pragma unroll
  for (int p = 0; p < 4; ++p) {
    u16 h0 = f2bf(v[2*p]), h1 = f2bf(v[2*p+1]);
    u16 l0 = f2bf(v[2*p] - bf2f(h0)), l1 = f2bf(v[2*p+1] - bf2f(h1));
    hw[p] = (unsigned)h0 | ((unsigned)h1 << 16);
    lw[p] = (unsigned)l0 | ((unsigned)l1 << 16);
  }
  *(uint4*)(xh + i) = make_uint4(hw[0], hw[1], hw[2], hw[3]);
  *(uint4*)(xl + i) = make_uint4(lw[0], lw[1], lw[2], lw[3]);
}

// src [R][C] fp32  ->  dh/dl [C][R] bf16 hi/lo   (transpose + split)
__global__ __launch_bounds__(256) void k_split_wT(const float* __restrict__ src,
                                                  u16* __restrict__ dh, u16* __restrict__ dl,
                                                  int R, int C) {
  __shared__ float t[32][33];
  const int tx = threadIdx.x & 31, ty = threadIdx.x >> 5;
  const int c0 = blockIdx.x * 32, r0 = blockIdx.y * 32;
#pragma unroll
  for (int i = 0; i < 4; ++i)
    t[ty + i * 8][tx] = src[(size_t)(r0 + ty + i * 8) * C + c0 + tx];
  __syncthreads();
#pragma unroll
  for (int i = 0; i < 4; ++i) {
    float v = t[tx][ty + i * 8];
    size_t o = (size_t)(c0 + ty + i * 8) * R + r0 + tx;
    u16 h = f2bf(v);
    dh[o] = h;
    dl[o] = f2bf(v - bf2f(h));
  }
}

// ---------------------------------------------------------------------------
// K1: H(split) = X @ W1. 128x128 tile, BK=32, 4 waves, coalesced staging.
// Chunk regions: Ah 0, Al 512, Bh 1024, Bl 1536
// ---------------------------------------------------------------------------
__global__ __launch_bounds__(256) void k_gemm1(const u16* __restrict__ Xh, const u16* __restrict__ Xl,
                                               const u16* __restrict__ W1ht, const u16* __restrict__ W1lt,
                                               u16* __restrict__ Hh, u16* __restrict__ Hl) {
  __shared__ u16 sm[2][2048 * 8];
  const int tid = threadIdx.x;
  const int lane = tid & 63, w = tid >> 6;
  const int wr = w >> 1, wc = w & 1;
  const int gm = blockIdx.y * 128, n0 = blockIdx.x * 128;

  const u16* srcbase = (w == 0) ? Xh : (w == 1) ? Xl : (w == 2) ? W1ht : W1lt;
  const int rowbase = (w < 2) ? gm : n0;
  const int st_row = lane >> 2;
  const int st_k16 = (lane & 3) ^ ((lane >> 3) & 3);

  f32x4 acc[4][4];
#pragma unroll
  for (int i = 0; i < 4; ++i)
#pragma unroll
    for (int j = 0; j < 4; ++j) acc[i][j] = (f32x4){0.f, 0.f, 0.f, 0.f};

  auto STAGE = [&](int buf, int kt) {
#pragma unroll
    for (int t = 0; t < 8; ++t) {
      const int row = rowbase + t * 16 + st_row;
      const u16* g = srcbase + ((size_t)row << 9) + (kt << 5) + st_k16 * 8;
      gload16(g, &sm[buf][(w * 512 + t * 64 + lane) * 8]);
    }
  };

  STAGE(0, 0);
  const int rI = (lane & 15) * 4 + ((lane >> 4) ^ ((lane >> 1) & 3));
  for (int kt = 0; kt < 16; ++kt) {
    __syncthreads();
    if (kt + 1 < 16) STAGE((kt + 1) & 1, kt + 1);
    const u16* base = sm[kt & 1];
    short8 ah[4], al[4], bh[4], bl[4];
#pragma unroll
    for (int i = 0; i < 4; ++i) {
      ah[i] = *(const short8*)(base + ((wr * 4 + i) * 64 + rI) * 8);
      al[i] = *(const short8*)(base + (512 + (wr * 4 + i) * 64 + rI) * 8);
      bh[i] = *(const short8*)(base + (1024 + (wc * 4 + i) * 64 + rI) * 8);
      bl[i] = *(const short8*)(base + (1536 + (wc * 4 + i) * 64 + rI) * 8);
    }
#pragma unroll
    for (int i = 0; i < 4; ++i)
#pragma unroll
      for (int j = 0; j < 4; ++j) {
        acc[i][j] = __builtin_amdgcn_mfma_f32_16x16x32_bf16(ah[i], bh[j], acc[i][j], 0, 0, 0);
        acc[i][j] = __builtin_amdgcn_mfma_f32_16x16x32_bf16(ah[i], bl[j], acc[i][j], 0, 0, 0);
        acc[i][j] = __builtin_amdgcn_mfma_f32_16x16x32_bf16(al[i], bh[j], acc[i][j], 0, 0, 0);
      }
  }

  const int rr = (lane >> 4) << 2, cc = lane & 15;
#pragma unroll
  for (int i = 0; i < 4; ++i)
#pragma unroll
    for (int j = 0; j < 4; ++j) {
#pragma unroll
      for (int reg = 0; reg < 4; ++reg) {
        size_t o = (size_t)(gm + wr * 64 + i * 16 + rr + reg) * CH + (n0 + wc * 64 + j * 16 + cc);
        float v = acc[i][j][reg];
        u16 h = f2bf(v);
        Hh[o] = h;
        Hl[o] = f2bf(v - bf2f(h));
      }
    }
}

// ---------------------------------------------------------------------------
// K2: in-place LayerNorm + ReLU on split H. One block per row.
// ---------------------------------------------------------------------------
__global__ __launch_bounds__(256) void k_ln(u16* __restrict__ Hh, u16* __restrict__ Hl,
                                            const float* __restrict__ g, const float* __restrict__ b) {
  __shared__ float red[8];
  const int row = blockIdx.x;
  const int tid = threadIdx.x;
  uint4* hp = (uint4*)(Hh + (size_t)row * CH);
  uint4* lp = (uint4*)(Hl + (size_t)row * CH);
  uint4 hh = hp[tid], ll = lp[tid];
  float f[8];
  {
    unsigned hw[4] = {hh.x, hh.y, hh.z, hh.w};
    unsigned lw[4] = {ll.x, ll.y, ll.z, ll.w};
#pragma unroll
    for (int p = 0; p < 4; ++p) {
      f[2*p]   = bf2f((u16)(hw[p] & 0xffffu)) + bf2f((u16)(lw[p] & 0xffffu));
      f[2*p+1] = bf2f((u16)(hw[p] >> 16))     + bf2f((u16)(lw[p] >> 16));
    }
  }
  float s = 0.f, ss = 0.f;
#pragma unroll
  for (int j = 0; j < 8; ++j) { s += f[j]; ss += f[j] * f[j]; }
#pragma unroll
  for (int m = 32; m; m >>= 1) { s += __shfl_xor(s, m); ss += __shfl_xor(ss, m); }
  if ((tid & 63) == 0) { red[(tid >> 6) * 2] = s; red[(tid >> 6) * 2 + 1] = ss; }
  __syncthreads();
  s  = red[0] + red[2] + red[4] + red[6];
  ss = red[1] + red[3] + red[5] + red[7];
  const float mu  = s * (1.f / CH);
  const float var = ss * (1.f / CH) - mu * mu;
  const float rinv = 1.f / sqrtf(var + 1e-5f);
  float4 g0 = ((const float4*)g)[tid * 2], g1 = ((const float4*)g)[tid * 2 + 1];
  float4 b0 = ((const float4*)b)[tid * 2], b1 = ((const float4*)b)[tid * 2 + 1];
  float gg[8] = {g0.x, g0.y, g0.z, g0.w, g1.x, g1.y, g1.z, g1.w};
  float bb[8] = {b0.x, b0.y, b0.z, b0.w, b1.x, b1.y, b1.z, b1.w};
  unsigned hw[4], lw[4];
#pragma unroll
  for (int p = 0; p < 4; ++p) {
    float y0 = fmaxf((f[2*p]   - mu) * rinv * gg[2*p]   + bb[2*p],   0.f);
    float y1 = fmaxf((f[2*p+1] - mu) * rinv * gg[2*p+1] + bb[2*p+1], 0.f);
    u16 h0 = f2bf(y0), h1 = f2bf(y1);
    u16 l0 = f2bf(y0 - bf2f(h0)), l1 = f2bf(y1 - bf2f(h1));
    hw[p] = (unsigned)h0 | ((unsigned)h1 << 16);
    lw[p] = (unsigned)l0 | ((unsigned)l1 << 16);
  }
  hp[tid] = make_uint4(hw[0], hw[1], hw[2], hw[3]);
  lp[tid] = make_uint4(lw[0], lw[1], lw[2], lw[3]);
}

// ---------------------------------------------------------------------------
// K3: fused Z = H @ W2 + b2 -> per-head LSE -> Z, EXh/EXl, SELF.
// Full N, BM=64, BN=256 (all heads in-block), BK=32, 8 waves (2x4).
// Chunk regions: Ah [0,256), Al [256,512), Bh [512,1536), Bl [1536,2560)
// ---------------------------------------------------------------------------
__global__ __launch_bounds__(512) void k_gemm2(const u16* __restrict__ Hh, const u16* __restrict__ Hl,
                                               const u16* __restrict__ W2ht, const u16* __restrict__ W2lt,
                                               const float* __restrict__ b2,
                                               float* __restrict__ Z,
                                               u16* __restrict__ EXh, u16* __restrict__ EXl,
                                               float* __restrict__ SELF) {
  __shared__ u16 sm[2][2560 * 8];   // 80 KB
  __shared__ float selfp[64][4];
  const int tid = threadIdx.x;
  const int lane = tid & 63, w = tid >> 6;
  const int wr = w >> 2, wc = w & 3;
  const int gm = blockIdx.x * 64;
  const int st_row = lane >> 2;
  const int st_k16 = (lane & 3) ^ ((lane >> 3) & 3);

  f32x4 acc[2][4];
#pragma unroll
  for (int i = 0; i < 2; ++i)
#pragma unroll
    for (int j = 0; j < 4; ++j) acc[i][j] = (f32x4){0.f, 0.f, 0.f, 0.f};

  auto STAGE = [&](int buf, int kt) {
#pragma unroll
    for (int t = 0; t < 5; ++t) {
      const int f = w * 5 + t;
      const u16* src;
      int tm, rowbase;
      if (f < 4)       { src = Hh;   tm = f;      rowbase = gm; }
      else if (f < 8)  { src = Hl;   tm = f - 4;  rowbase = gm; }
      else if (f < 24) { src = W2ht; tm = f - 8;  rowbase = 0;  }
      else             { src = W2lt; tm = f - 24; rowbase = 0;  }
      const int row = rowbase + tm * 16 + st_row;
      const u16* g = src + ((size_t)row << 11) + (kt << 5) + st_k16 * 8;
      gload16(g, &sm[buf][(f * 64 + lane) * 8]);
    }
  };

  STAGE(0, 0);
  const int rI = (lane & 15) * 4 + ((lane >> 4) ^ ((lane >> 1) & 3));
  for (int kt = 0; kt < 64; ++kt) {
    __syncthreads();
    if (kt + 1 < 64) STAGE((kt + 1) & 1, kt + 1);
    const u16* base = sm[kt & 1];
    short8 ah[2], al[2], bh[4], bl[4];
#pragma unroll
    for (int i = 0; i < 2; ++i) {
      ah[i] = *(const short8*)(base + ((wr * 2 + i) * 64 + rI) * 8);
      al[i] = *(const short8*)(base + (256 + (wr * 2 + i) * 64 + rI) * 8);
    }
#pragma unroll
    for (int j = 0; j < 4; ++j) {
      bh[j] = *(const short8*)(base + (512 + (wc * 4 + j) * 64 + rI) * 8);
      bl[j] = *(const short8*)(base + (1536 + (wc * 4 + j) * 64 + rI) * 8);
    }
#pragma unroll
    for (int i = 0; i < 2; ++i)
#pragma unroll
      for (int j = 0; j < 4; ++j) {
        acc[i][j] = __builtin_amdgcn_mfma_f32_16x16x32_bf16(ah[i], bh[j], acc[i][j], 0, 0, 0);
        acc[i][j] = __builtin_amdgcn_mfma_f32_16x16x32_bf16(ah[i], bl[j], acc[i][j], 0, 0, 0);
        acc[i][j] = __builtin_amdgcn_mfma_f32_16x16x32_bf16(al[i], bh[j], acc[i][j], 0, 0, 0);
      }
  }

  // fused epilogue: bias + per-head (64-col, == this wave's wc) LSE
  const int cc = lane & 15;
  float bias[4];
#pragma unroll
  for (int j = 0; j < 4; ++j) bias[j] = b2[wc * 64 + j * 16 + cc];

#pragma unroll
  for (int i = 0; i < 2; ++i)
#pragma unroll
    for (int reg = 0; reg < 4; ++reg) {
      const int rl = wr * 32 + i * 16 + ((lane >> 4) << 2) + reg;   // row in [0,64)
      const int row = gm + rl;
      float z[4];
#pragma unroll
      for (int j = 0; j < 4; ++j) z[j] = acc[i][j][reg] + bias[j];
      float mx = fmaxf(fmaxf(z[0], z[1]), fmaxf(z[2], z[3]));
#pragma unroll
      for (int m = 1; m <= 8; m <<= 1) mx = fmaxf(mx, __shfl_xor(mx, m));
      float se = expf(z[0] - mx) + expf(z[1] - mx) + expf(z[2] - mx) + expf(z[3] - mx);
#pragma unroll
      for (int m = 1; m <= 8; m <<= 1) se += __shfl_xor(se, m);
      const float lse = mx + logf(se);
      float selfc = 0.f;
#pragma unroll
      for (int j = 0; j < 4; ++j) {
        const float p = z[j] - lse;
        const float e = expf(p);
        selfc += e * p;
        const size_t o = (size_t)row * DD + wc * 64 + j * 16 + cc;
        Z[o] = z[j];
        u16 h = f2bf(e);
        EXh[o] = h;
        EXl[o] = f2bf(e - bf2f(h));
      }
#pragma unroll
      for (int m = 1; m <= 8; m <<= 1) selfc += __shfl_xor(selfc, m);
      if (cc == 0) selfp[rl][wc] = selfc;
    }
  __syncthreads();
  if (tid < 64)
    SELF[gm + tid] = selfp[tid][0] + selfp[tid][1] + selfp[tid][2] + selfp[tid][3];
}

// ---------------------------------------------------------------------------
// K4: logE = log(emb), 3-split bf16 (hi/mid/lo), layout [1024][256]
// ---------------------------------------------------------------------------
__global__ __launch_bounds__(256) void k_prep_le(const float* __restrict__ E,
                                                 u16* __restrict__ LEh, u16* __restrict__ LEm,
                                                 u16* __restrict__ LEl) {
  const size_t i = ((size_t)blockIdx.x * 256 + threadIdx.x) * 4;
  float4 v4 = *(const float4*)&E[i];
  float v[4] = {logf(v4.x), logf(v4.y), logf(v4.z), logf(v4.w)};
  u16 h[4], m_[4], l[4];
#pragma unroll
  for (int e = 0; e < 4; ++e) {
    h[e] = f2bf(v[e]);
    float r1 = v[e] - bf2f(h[e]);
    m_[e] = f2bf(r1);
    float r2 = r1 - bf2f(m_[e]);
    l[e] = f2bf(r2);
  }
  *(uint2*)&LEh[i] = make_uint2((unsigned)h[0] | ((unsigned)h[1] << 16), (unsigned)h[2] | ((unsigned)h[3] << 16));
  *(uint2*)&LEm[i] = make_uint2((unsigned)m_[0] | ((unsigned)m_[1] << 16), (unsigned)m_[2] | ((unsigned)m_[3] << 16));
  *(uint2*)&LEl[i] = make_uint2((unsigned)l[0] | ((unsigned)l[1] << 16), (unsigned)l[2] | ((unsigned)l[3] << 16));
}

// ---------------------------------------------------------------------------
// K5: DOTS[N,1024] = EX @ LE^T (5-term split MFMA), coalesced staging.
// 128x128 tile, BK=32, K=256. Regions: EXh 0, EXl 512, LEh 1024, LEm 1536, LEl 2048
// ---------------------------------------------------------------------------
__global__ __launch_bounds__(256) void k_dots(const u16* __restrict__ EXh, const u16* __restrict__ EXl,
                                              const u16* __restrict__ LEh, const u16* __restrict__ LEm,
                                              const u16* __restrict__ LEl,
                                              float* __restrict__ DOTS) {
  __shared__ u16 sm[2560 * 8];
  const int tid = threadIdx.x;
  const int lane = tid & 63, w = tid >> 6;
  const int wr = w >> 1, wc = w & 1;
  const int gm = blockIdx.y * 128, m0 = blockIdx.x * 128;
  const int st_row = lane >> 2;
  const int st_k16 = (lane & 3) ^ ((lane >> 3) & 3);

  f32x4 acc[4][4];
#pragma unroll
  for (int i = 0; i < 4; ++i)
#pragma unroll
    for (int j = 0; j < 4; ++j) acc[i][j] = (f32x4){0.f, 0.f, 0.f, 0.f};

  const int rI = (lane & 15) * 4 + ((lane >> 4) ^ ((lane >> 1) & 3));
  for (int kt = 0; kt < 8; ++kt) {
    __syncthreads();
#pragma unroll
    for (int t = 0; t < 10; ++t) {
      const int f = w * 10 + t;
      const int mtx = f >> 3, tm = f & 7;
      const u16* src = (mtx == 0) ? EXh : (mtx == 1) ? EXl :
                       (mtx == 2) ? LEh : (mtx == 3) ? LEm : LEl;
      const int rowbase = (mtx < 2) ? gm : m0;
      const int row = rowbase + tm * 16 + st_row;
      const u16* g = src + ((size_t)row << 8) + (kt << 5) + st_k16 * 8;
      gload16(g, &sm[(f * 64 + lane) * 8]);
    }
    __syncthreads();
    short8 eh[4], el[4], bh[4], bm[4], bl[4];
#pragma unroll
    for (int i = 0; i < 4; ++i) {
      eh[i] = *(const short8*)(sm + ((wr * 4 + i) * 64 + rI) * 8);
      el[i] = *(const short8*)(sm + (512 + (wr * 4 + i) * 64 + rI) * 8);
      bh[i] = *(const short8*)(sm + (1024 + (wc * 4 + i) * 64 + rI) * 8);
      bm[i] = *(const short8*)(sm + (1536 + (wc * 4 + i) * 64 + rI) * 8);
      bl[i] = *(const short8*)(sm + (2048 + (wc * 4 + i) * 64 + rI) * 8);
    }
#pragma unroll
    for (int i = 0; i < 4; ++i)
#pragma unroll
      for (int j = 0; j < 4; ++j) {
        acc[i][j] = __builtin_amdgcn_mfma_f32_16x16x32_bf16(eh[i], bh[j], acc[i][j], 0, 0, 0);
        acc[i][j] = __builtin_amdgcn_mfma_f32_16x16x32_bf16(eh[i], bm[j], acc[i][j], 0, 0, 0);
        acc[i][j] = __builtin_amdgcn_mfma_f32_16x16x32_bf16(eh[i], bl[j], acc[i][j], 0, 0, 0);
        acc[i][j] = __builtin_amdgcn_mfma_f32_16x16x32_bf16(el[i], bh[j], acc[i][j], 0, 0, 0);
        acc[i][j] = __builtin_amdgcn_mfma_f32_16x16x32_bf16(el[i], bm[j], acc[i][j], 0, 0, 0);
      }
  }

  const int rr = (lane >> 4) << 2, cc = lane & 15;
#pragma unroll
  for (int i = 0; i < 4; ++i)
#pragma unroll
    for (int j = 0; j < 4; ++j)
#pragma unroll
      for (int reg = 0; reg < 4; ++reg) {
        const int row = gm + wr * 64 + i * 16 + rr + reg;
        const int col = m0 + wc * 64 + j * 16 + cc;
        DOTS[((size_t)row << 10) + col] = acc[i][j][reg];
      }
}

// ---------------------------------------------------------------------------
// K6: per row: argmax(dots), KL = self - max, fused gather Q. Wave per row.
// ---------------------------------------------------------------------------
__global__ __launch_bounds__(256) void k_scan(const float* __restrict__ DOTS,
                                              const float* __restrict__ SELF,
                                              const float* __restrict__ E,
                                              float* __restrict__ Q,
                                              float* __restrict__ KL) {
  const int tid = threadIdx.x;
  const int lane = tid & 63;
  const int row = blockIdx.x * 4 + (tid >> 6);

  float bv = -1e30f;
  int bi = 0x7fffffff;
#pragma unroll
  for (int q = 0; q < 4; ++q) {
    const int c0 = q * 256 + lane * 4;
    float4 v = *(const float4*)&DOTS[((size_t)row << 10) + c0];
    if (v.x > bv) { bv = v.x; bi = c0; }
    if (v.y > bv) { bv = v.y; bi = c0 + 1; }
    if (v.z > bv) { bv = v.z; bi = c0 + 2; }
    if (v.w > bv) { bv = v.w; bi = c0 + 3; }
  }
#pragma unroll
  for (int m = 32; m; m >>= 1) {
    float ov = __shfl_xor(bv, m);
    int   oi = __shfl_xor(bi, m);
    if (ov > bv || (ov == bv && oi < bi)) { bv = ov; bi = oi; }
  }
  if (lane == 0) KL[row] = SELF[row] - bv;
  float4 e4 = *(const float4*)&E[((size_t)bi << 8) + lane * 4];
  *(float4*)&Q[((size_t)row << 8) + lane * 4] = e4;
}

// ---------------------------------------------------------------------------
// K7: loss = 0.25/B * sum_n kl[n]*mask[n]
// ---------------------------------------------------------------------------
__global__ __launch_bounds__(256) void k_loss(const float* __restrict__ KL,
                                              const float* __restrict__ MASK,
                                              float* __restrict__ out) {
  __shared__ float red[4];
  const int tid = threadIdx.x;
  float s = 0.f;
  for (int i = tid; i < NROWS; i += 256) s += KL[i] * MASK[i];
#pragma unroll
  for (int m = 32; m; m >>= 1) s += __shfl_xor(s, m);
  if ((tid & 63) == 0) red[tid >> 6] = s;
  __syncthreads();
  if (tid == 0) out[0] = (red[0] + red[1] + red[2] + red[3]) * (0.25f / 16.f);
}

// ---------------------------------------------------------------------------
extern "C" void kernel_launch(void* const* d_in, const int* in_sizes, int n_in,
                              void* d_out, int out_size, void* d_ws, size_t ws_size,
                              hipStream_t stream) {
  const float* x     = (const float*)d_in[0];
  const float* masks = (const float*)d_in[1];
  const float* W1    = (const float*)d_in[2];
  const float* ln_g  = (const float*)d_in[3];
  const float* ln_b  = (const float*)d_in[4];
  const float* W2    = (const float*)d_in[5];
  const float* b2    = (const float*)d_in[6];
  const float* emb   = (const float*)d_in[7];

  float* z_out = (float*)d_out;
  float* q_out = z_out + (size_t)NROWS * DD;
  float* loss_out = z_out + 2 * (size_t)NROWS * DD;

  char* ws = (char*)d_ws;
  u16*   Hh   = (u16*)(ws);                    //  67,108,864 (16384x2048)
  u16*   Hl   = (u16*)(ws + 67108864);         //  67,108,864
  u16*   W1ht = (u16*)(ws + 134217728);        //   2,097,152
  u16*   W1lt = (u16*)(ws + 136314880);        //   2,097,152
  u16*   W2ht = (u16*)(ws + 138412032);        //   1,048,576
  u16*   W2lt = (u16*)(ws + 139460608);        //   1,048,576
  u16*   LEh  = (u16*)(ws + 140509184);        //     524,288
  u16*   LEm  = (u16*)(ws + 141033472);        //     524,288
  u16*   LEl  = (u16*)(ws + 141557760);        //     524,288
  float* SELF = (float*)(ws + 142082048);      //      65,536
  float* KL   = (float*)(ws + 142147584);      //      65,536
  u16*   Xh   = (u16*)(ws + 142213120);        //   4,194,304 (quarter 4096x512)
  u16*   Xl   = (u16*)(ws + 146407424);        //   4,194,304 -> end 150,601,728
  float* DOTS = (float*)(ws);                  //  67,108,864 overlay (H dead after gemm2)
  // EX scratch lives in q_out (16 MB), overwritten later by k_scan's Q:
  u16*   EXh  = (u16*)q_out;                   //   8,388,608
  u16*   EXl  = EXh + (size_t)NROWS * DD;      //   8,388,608

  k_split_wT<<<dim3(64, 16), 256, 0, stream>>>(W1, W1ht, W1lt, INCH, CH);
  k_split_wT<<<dim3(8, 64), 256, 0, stream>>>(W2, W2ht, W2lt, CH, DD);
  k_prep_le<<<256, 256, 0, stream>>>(emb, LEh, LEm, LEl);

  for (int q = 0; q < 4; ++q) {
    const size_t xo = (size_t)q * QROWS * INCH;
    const size_t ho = (size_t)q * QROWS * CH;
    k_split_x<<<1024, 256, 0, stream>>>(x + xo, Xh, Xl);
    k_gemm1<<<dim3(16, 32), 256, 0, stream>>>(Xh, Xl, W1ht, W1lt, Hh + ho, Hl + ho);
  }
  k_ln<<<NROWS, 256, 0, stream>>>(Hh, Hl, ln_g, ln_b);
  k_gemm2<<<NROWS / 64, 512, 0, stream>>>(Hh, Hl, W2ht, W2lt, b2, z_out, EXh, EXl, SELF);

  k_dots<<<dim3(8, 128), 256, 0, stream>>>(EXh, EXl, LEh, LEm, LEl, DOTS);
  k_scan<<<4096, 256, 0, stream>>>(DOTS, SELF, emb, q_out, KL);
  k_loss<<<1, 256, 0, stream>>>(KL, masks, loss_out);
}

// Round 6
// 375.603 us; speedup vs baseline: 2.2638x; 1.0002x over previous
//
#include <hip/hip_runtime.h>
#include <math.h>

#define NROWS 16384   // B*T
#define QROWS 4096
#define INCH  512
#define CH    2048
#define DD    256
#define MM    1024

typedef unsigned short u16;
typedef short short8 __attribute__((ext_vector_type(8)));
typedef float f32x4 __attribute__((ext_vector_type(4)));

__device__ __forceinline__ u16 f2bf(float f) {
  unsigned u = __float_as_uint(f);
  return (u16)((u + 0x7fffu + ((u >> 16) & 1u)) >> 16);
}
__device__ __forceinline__ float bf2f(u16 h) {
  return __uint_as_float(((unsigned)h) << 16);
}
__device__ __forceinline__ void gload16(const u16* g, u16* lds) {
  __builtin_amdgcn_global_load_lds((const __attribute__((address_space(1))) void*)g,
                                   (__attribute__((address_space(3))) void*)lds, 16, 0, 0);
}

// Coalesced-staging chunk mapping (16B chunks of 8 bf16 along K):
//   staging instr t, lane i: row = t*16 + (i>>2), k16 = (i&3) ^ ((i>>3)&3),
//                            LDS slot = t*64 + i  (linear in lane -> gload_lds OK)
//   read (MFMA frag): chunk = (rowoff>>4)*64 + rI,
//   rI = (lane&15)*4 + ((lane>>4) ^ ((lane>>1)&3))  -> 2-way banks (free)

// ---------------------------------------------------------------------------
// split: fp32 -> bf16 hi/lo pair (quarter: 4096x512)
// ---------------------------------------------------------------------------
__global__ __launch_bounds__(256) void k_split_x(const float* __restrict__ x,
                                                 u16* __restrict__ xh, u16* __restrict__ xl) {
  const size_t i = ((size_t)blockIdx.x * 256 + threadIdx.x) * 8;
  float4 a = *(const float4*)(x + i);
  float4 b = *(const float4*)(x + i + 4);
  float v[8] = {a.x, a.y, a.z, a.w, b.x, b.y, b.z, b.w};
  unsigned hw[4], lw[4];
#pragma unroll
  for (int p = 0; p < 4; ++p) {
    u16 h0 = f2bf(v[2*p]), h1 = f2bf(v[2*p+1]);
    u16 l0 = f2bf(v[2*p] - bf2f(h0)), l1 = f2bf(v[2*p+1] - bf2f(h1));
    hw[p] = (unsigned)h0 | ((unsigned)h1 << 16);
    lw[p] = (unsigned)l0 | ((unsigned)l1 << 16);
  }
  *(uint4*)(xh + i) = make_uint4(hw[0], hw[1], hw[2], hw[3]);
  *(uint4*)(xl + i) = make_uint4(lw[0], lw[1], lw[2], lw[3]);
}

// src [R][C] fp32  ->  dh/dl [C][R] bf16 hi/lo   (transpose + split)
__global__ __launch_bounds__(256) void k_split_wT(const float* __restrict__ src,
                                                  u16* __restrict__ dh, u16* __restrict__ dl,
                                                  int R, int C) {
  __shared__ float t[32][33];
  const int tx = threadIdx.x & 31, ty = threadIdx.x >> 5;
  const int c0 = blockIdx.x * 32, r0 = blockIdx.y * 32;
#pragma unroll
  for (int i = 0; i < 4; ++i)
    t[ty + i * 8][tx] = src[(size_t)(r0 + ty + i * 8) * C + c0 + tx];
  __syncthreads();
#pragma unroll
  for (int i = 0; i < 4; ++i) {
    float v = t[tx][ty + i * 8];
    size_t o = (size_t)(c0 + ty + i * 8) * R + r0 + tx;
    u16 h = f2bf(v);
    dh[o] = h;
    dl[o] = f2bf(v - bf2f(h));
  }
}

// ---------------------------------------------------------------------------
// K1: H(split) = X @ W1. 128x128 tile, BK=32, 4 waves, coalesced staging,
// LDS-staged coalesced epilogue. Chunk regions: Ah 0, Al 512, Bh 1024, Bl 1536
// ---------------------------------------------------------------------------
__global__ __launch_bounds__(256) void k_gemm1(const u16* __restrict__ Xh, const u16* __restrict__ Xl,
                                               const u16* __restrict__ W1ht, const u16* __restrict__ W1lt,
                                               u16* __restrict__ Hh, u16* __restrict__ Hl) {
  __shared__ u16 sm[2][2112 * 8];   // loop uses 2048 chunks/buf; epilogue fp32 [128][132]
  const int tid = threadIdx.x;
  const int lane = tid & 63, w = tid >> 6;
  const int wr = w >> 1, wc = w & 1;
  const int gm = blockIdx.y * 128, n0 = blockIdx.x * 128;

  const u16* srcbase = (w == 0) ? Xh : (w == 1) ? Xl : (w == 2) ? W1ht : W1lt;
  const int rowbase = (w < 2) ? gm : n0;
  const int st_row = lane >> 2;
  const int st_k16 = (lane & 3) ^ ((lane >> 3) & 3);

  f32x4 acc[4][4];
#pragma unroll
  for (int i = 0; i < 4; ++i)
#pragma unroll
    for (int j = 0; j < 4; ++j) acc[i][j] = (f32x4){0.f, 0.f, 0.f, 0.f};

  auto STAGE = [&](int buf, int kt) {
#pragma unroll
    for (int t = 0; t < 8; ++t) {
      const int row = rowbase + t * 16 + st_row;
      const u16* g = srcbase + ((size_t)row << 9) + (kt << 5) + st_k16 * 8;
      gload16(g, &sm[buf][(w * 512 + t * 64 + lane) * 8]);
    }
  };

  STAGE(0, 0);
  const int rI = (lane & 15) * 4 + ((lane >> 4) ^ ((lane >> 1) & 3));
  for (int kt = 0; kt < 16; ++kt) {
    __syncthreads();
    if (kt + 1 < 16) STAGE((kt + 1) & 1, kt + 1);
    const u16* base = sm[kt & 1];
    short8 ah[4], al[4], bh[4], bl[4];
#pragma unroll
    for (int i = 0; i < 4; ++i) {
      ah[i] = *(const short8*)(base + ((wr * 4 + i) * 64 + rI) * 8);
      al[i] = *(const short8*)(base + (512 + (wr * 4 + i) * 64 + rI) * 8);
      bh[i] = *(const short8*)(base + (1024 + (wc * 4 + i) * 64 + rI) * 8);
      bl[i] = *(const short8*)(base + (1536 + (wc * 4 + i) * 64 + rI) * 8);
    }
#pragma unroll
    for (int i = 0; i < 4; ++i)
#pragma unroll
      for (int j = 0; j < 4; ++j) {
        acc[i][j] = __builtin_amdgcn_mfma_f32_16x16x32_bf16(ah[i], bh[j], acc[i][j], 0, 0, 0);
        acc[i][j] = __builtin_amdgcn_mfma_f32_16x16x32_bf16(ah[i], bl[j], acc[i][j], 0, 0, 0);
        acc[i][j] = __builtin_amdgcn_mfma_f32_16x16x32_bf16(al[i], bh[j], acc[i][j], 0, 0, 0);
      }
  }

  // ---- LDS-staged coalesced epilogue ----
  __syncthreads();                          // all LDS reads of sm done
  float* smf = (float*)&sm[0][0];           // view: [128][132] fp32
  const int rr = (lane >> 4) << 2, cc = lane & 15;
#pragma unroll
  for (int i = 0; i < 4; ++i)
#pragma unroll
    for (int j = 0; j < 4; ++j)
#pragma unroll
      for (int reg = 0; reg < 4; ++reg)
        smf[(wr * 64 + i * 16 + rr + reg) * 132 + (wc * 64 + j * 16 + cc)] = acc[i][j][reg];
  __syncthreads();
  const int trow = tid >> 4, tcg = tid & 15;
#pragma unroll
  for (int rr2 = 0; rr2 < 8; ++rr2) {
    const int r = rr2 * 16 + trow;
    float v[8];
    *(f32x4*)&v[0] = *(const f32x4*)&smf[r * 132 + tcg * 8];
    *(f32x4*)&v[4] = *(const f32x4*)&smf[r * 132 + tcg * 8 + 4];
    unsigned hw[4], lw[4];
#pragma unroll
    for (int p = 0; p < 4; ++p) {
      u16 h0 = f2bf(v[2*p]), h1 = f2bf(v[2*p+1]);
      u16 l0 = f2bf(v[2*p] - bf2f(h0)), l1 = f2bf(v[2*p+1] - bf2f(h1));
      hw[p] = (unsigned)h0 | ((unsigned)h1 << 16);
      lw[p] = (unsigned)l0 | ((unsigned)l1 << 16);
    }
    const size_t o = (size_t)(gm + r) * CH + n0 + tcg * 8;
    *(uint4*)&Hh[o] = make_uint4(hw[0], hw[1], hw[2], hw[3]);
    *(uint4*)&Hl[o] = make_uint4(lw[0], lw[1], lw[2], lw[3]);
  }
}

// ---------------------------------------------------------------------------
// K2: in-place LayerNorm + ReLU on split H. One block per row.
// ---------------------------------------------------------------------------
__global__ __launch_bounds__(256) void k_ln(u16* __restrict__ Hh, u16* __restrict__ Hl,
                                            const float* __restrict__ g, const float* __restrict__ b) {
  __shared__ float red[8];
  const int row = blockIdx.x;
  const int tid = threadIdx.x;
  uint4* hp = (uint4*)(Hh + (size_t)row * CH);
  uint4* lp = (uint4*)(Hl + (size_t)row * CH);
  uint4 hh = hp[tid], ll = lp[tid];
  float f[8];
  {
    unsigned hw[4] = {hh.x, hh.y, hh.z, hh.w};
    unsigned lw[4] = {ll.x, ll.y, ll.z, ll.w};
#pragma unroll
    for (int p = 0; p < 4; ++p) {
      f[2*p]   = bf2f((u16)(hw[p] & 0xffffu)) + bf2f((u16)(lw[p] & 0xffffu));
      f[2*p+1] = bf2f((u16)(hw[p] >> 16))     + bf2f((u16)(lw[p] >> 16));
    }
  }
  float s = 0.f, ss = 0.f;
#pragma unroll
  for (int j = 0; j < 8; ++j) { s += f[j]; ss += f[j] * f[j]; }
#pragma unroll
  for (int m = 32; m; m >>= 1) { s += __shfl_xor(s, m); ss += __shfl_xor(ss, m); }
  if ((tid & 63) == 0) { red[(tid >> 6) * 2] = s; red[(tid >> 6) * 2 + 1] = ss; }
  __syncthreads();
  s  = red[0] + red[2] + red[4] + red[6];
  ss = red[1] + red[3] + red[5] + red[7];
  const float mu  = s * (1.f / CH);
  const float var = ss * (1.f / CH) - mu * mu;
  const float rinv = 1.f / sqrtf(var + 1e-5f);
  float4 g0 = ((const float4*)g)[tid * 2], g1 = ((const float4*)g)[tid * 2 + 1];
  float4 b0 = ((const float4*)b)[tid * 2], b1 = ((const float4*)b)[tid * 2 + 1];
  float gg[8] = {g0.x, g0.y, g0.z, g0.w, g1.x, g1.y, g1.z, g1.w};
  float bb[8] = {b0.x, b0.y, b0.z, b0.w, b1.x, b1.y, b1.z, b1.w};
  unsigned hw[4], lw[4];
#pragma unroll
  for (int p = 0; p < 4; ++p) {
    float y0 = fmaxf((f[2*p]   - mu) * rinv * gg[2*p]   + bb[2*p],   0.f);
    float y1 = fmaxf((f[2*p+1] - mu) * rinv * gg[2*p+1] + bb[2*p+1], 0.f);
    u16 h0 = f2bf(y0), h1 = f2bf(y1);
    u16 l0 = f2bf(y0 - bf2f(h0)), l1 = f2bf(y1 - bf2f(h1));
    hw[p] = (unsigned)h0 | ((unsigned)h1 << 16);
    lw[p] = (unsigned)l0 | ((unsigned)l1 << 16);
  }
  hp[tid] = make_uint4(hw[0], hw[1], hw[2], hw[3]);
  lp[tid] = make_uint4(lw[0], lw[1], lw[2], lw[3]);
}

// ---------------------------------------------------------------------------
// K3: fused Z = H @ W2 + b2 -> per-head LSE -> Z, EXh/EXl, SELF.
// Full N, BM=64, BN=256 (all heads in-block), BK=32, 8 waves (2x4).
// ---------------------------------------------------------------------------
__global__ __launch_bounds__(512) void k_gemm2(const u16* __restrict__ Hh, const u16* __restrict__ Hl,
                                               const u16* __restrict__ W2ht, const u16* __restrict__ W2lt,
                                               const float* __restrict__ b2,
                                               float* __restrict__ Z,
                                               u16* __restrict__ EXh, u16* __restrict__ EXl,
                                               float* __restrict__ SELF) {
  __shared__ u16 sm[2][2560 * 8];   // 80 KB
  __shared__ float selfp[64][4];
  const int tid = threadIdx.x;
  const int lane = tid & 63, w = tid >> 6;
  const int wr = w >> 2, wc = w & 3;
  const int gm = blockIdx.x * 64;
  const int st_row = lane >> 2;
  const int st_k16 = (lane & 3) ^ ((lane >> 3) & 3);

  f32x4 acc[2][4];
#pragma unroll
  for (int i = 0; i < 2; ++i)
#pragma unroll
    for (int j = 0; j < 4; ++j) acc[i][j] = (f32x4){0.f, 0.f, 0.f, 0.f};

  auto STAGE = [&](int buf, int kt) {
#pragma unroll
    for (int t = 0; t < 5; ++t) {
      const int f = w * 5 + t;
      const u16* src;
      int tm, rowbase;
      if (f < 4)       { src = Hh;   tm = f;      rowbase = gm; }
      else if (f < 8)  { src = Hl;   tm = f - 4;  rowbase = gm; }
      else if (f < 24) { src = W2ht; tm = f - 8;  rowbase = 0;  }
      else             { src = W2lt; tm = f - 24; rowbase = 0;  }
      const int row = rowbase + tm * 16 + st_row;
      const u16* g = src + ((size_t)row << 11) + (kt << 5) + st_k16 * 8;
      gload16(g, &sm[buf][(f * 64 + lane) * 8]);
    }
  };

  STAGE(0, 0);
  const int rI = (lane & 15) * 4 + ((lane >> 4) ^ ((lane >> 1) & 3));
  for (int kt = 0; kt < 64; ++kt) {
    __syncthreads();
    if (kt + 1 < 64) STAGE((kt + 1) & 1, kt + 1);
    const u16* base = sm[kt & 1];
    short8 ah[2], al[2], bh[4], bl[4];
#pragma unroll
    for (int i = 0; i < 2; ++i) {
      ah[i] = *(const short8*)(base + ((wr * 2 + i) * 64 + rI) * 8);
      al[i] = *(const short8*)(base + (256 + (wr * 2 + i) * 64 + rI) * 8);
    }
#pragma unroll
    for (int j = 0; j < 4; ++j) {
      bh[j] = *(const short8*)(base + (512 + (wc * 4 + j) * 64 + rI) * 8);
      bl[j] = *(const short8*)(base + (1536 + (wc * 4 + j) * 64 + rI) * 8);
    }
#pragma unroll
    for (int i = 0; i < 2; ++i)
#pragma unroll
      for (int j = 0; j < 4; ++j) {
        acc[i][j] = __builtin_amdgcn_mfma_f32_16x16x32_bf16(ah[i], bh[j], acc[i][j], 0, 0, 0);
        acc[i][j] = __builtin_amdgcn_mfma_f32_16x16x32_bf16(ah[i], bl[j], acc[i][j], 0, 0, 0);
        acc[i][j] = __builtin_amdgcn_mfma_f32_16x16x32_bf16(al[i], bh[j], acc[i][j], 0, 0, 0);
      }
  }

  // fused epilogue: bias + per-head (64-col == this wave's wc) LSE
  const int cc = lane & 15;
  float bias[4];
#pragma unroll
  for (int j = 0; j < 4; ++j) bias[j] = b2[wc * 64 + j * 16 + cc];

#pragma unroll
  for (int i = 0; i < 2; ++i)
#pragma unroll
    for (int reg = 0; reg < 4; ++reg) {
      const int rl = wr * 32 + i * 16 + ((lane >> 4) << 2) + reg;   // row in [0,64)
      const int row = gm + rl;
      float z[4];
#pragma unroll
      for (int j = 0; j < 4; ++j) z[j] = acc[i][j][reg] + bias[j];
      float mx = fmaxf(fmaxf(z[0], z[1]), fmaxf(z[2], z[3]));
#pragma unroll
      for (int m = 1; m <= 8; m <<= 1) mx = fmaxf(mx, __shfl_xor(mx, m));
      float se = expf(z[0] - mx) + expf(z[1] - mx) + expf(z[2] - mx) + expf(z[3] - mx);
#pragma unroll
      for (int m = 1; m <= 8; m <<= 1) se += __shfl_xor(se, m);
      const float lse = mx + logf(se);
      float selfc = 0.f;
#pragma unroll
      for (int j = 0; j < 4; ++j) {
        const float p = z[j] - lse;
        const float e = expf(p);
        selfc += e * p;
        const size_t o = (size_t)row * DD + wc * 64 + j * 16 + cc;
        Z[o] = z[j];
        u16 h = f2bf(e);
        EXh[o] = h;
        EXl[o] = f2bf(e - bf2f(h));
      }
#pragma unroll
      for (int m = 1; m <= 8; m <<= 1) selfc += __shfl_xor(selfc, m);
      if (cc == 0) selfp[rl][wc] = selfc;
    }
  __syncthreads();
  if (tid < 64)
    SELF[gm + tid] = selfp[tid][0] + selfp[tid][1] + selfp[tid][2] + selfp[tid][3];
}

// ---------------------------------------------------------------------------
// K4: logE = log(emb), 3-split bf16 (hi/mid/lo), layout [1024][256]
// ---------------------------------------------------------------------------
__global__ __launch_bounds__(256) void k_prep_le(const float* __restrict__ E,
                                                 u16* __restrict__ LEh, u16* __restrict__ LEm,
                                                 u16* __restrict__ LEl) {
  const size_t i = ((size_t)blockIdx.x * 256 + threadIdx.x) * 4;
  float4 v4 = *(const float4*)&E[i];
  float v[4] = {logf(v4.x), logf(v4.y), logf(v4.z), logf(v4.w)};
  u16 h[4], m_[4], l[4];
#pragma unroll
  for (int e = 0; e < 4; ++e) {
    h[e] = f2bf(v[e]);
    float r1 = v[e] - bf2f(h[e]);
    m_[e] = f2bf(r1);
    float r2 = r1 - bf2f(m_[e]);
    l[e] = f2bf(r2);
  }
  *(uint2*)&LEh[i] = make_uint2((unsigned)h[0] | ((unsigned)h[1] << 16), (unsigned)h[2] | ((unsigned)h[3] << 16));
  *(uint2*)&LEm[i] = make_uint2((unsigned)m_[0] | ((unsigned)m_[1] << 16), (unsigned)m_[2] | ((unsigned)m_[3] << 16));
  *(uint2*)&LEl[i] = make_uint2((unsigned)l[0] | ((unsigned)l[1] << 16), (unsigned)l[2] | ((unsigned)l[3] << 16));
}

// ---------------------------------------------------------------------------
// K5: dots = EX @ LE^T (5-term split MFMA) with FUSED per-tile argmax.
// Writes PV/PI [N][16] partials only (no DOTS matrix).
// 128x128 tile, BK=32, K=256. Regions: EXh 0, EXl 512, LEh 1024, LEm 1536, LEl 2048
// ---------------------------------------------------------------------------
__global__ __launch_bounds__(256) void k_dots(const u16* __restrict__ EXh, const u16* __restrict__ EXl,
                                              const u16* __restrict__ LEh, const u16* __restrict__ LEm,
                                              const u16* __restrict__ LEl,
                                              float* __restrict__ PV, int* __restrict__ PI) {
  __shared__ u16 sm[2560 * 8];
  const int tid = threadIdx.x;
  const int lane = tid & 63, w = tid >> 6;
  const int wr = w >> 1, wc = w & 1;
  const int gm = blockIdx.y * 128, m0 = blockIdx.x * 128;
  const int st_row = lane >> 2;
  const int st_k16 = (lane & 3) ^ ((lane >> 3) & 3);

  f32x4 acc[4][4];
#pragma unroll
  for (int i = 0; i < 4; ++i)
#pragma unroll
    for (int j = 0; j < 4; ++j) acc[i][j] = (f32x4){0.f, 0.f, 0.f, 0.f};

  const int rI = (lane & 15) * 4 + ((lane >> 4) ^ ((lane >> 1) & 3));
  for (int kt = 0; kt < 8; ++kt) {
    __syncthreads();
#pragma unroll
    for (int t = 0; t < 10; ++t) {
      const int f = w * 10 + t;
      const int mtx = f >> 3, tm = f & 7;
      const u16* src = (mtx == 0) ? EXh : (mtx == 1) ? EXl :
                       (mtx == 2) ? LEh : (mtx == 3) ? LEm : LEl;
      const int rowbase = (mtx < 2) ? gm : m0;
      const int row = rowbase + tm * 16 + st_row;
      const u16* g = src + ((size_t)row << 8) + (kt << 5) + st_k16 * 8;
      gload16(g, &sm[(f * 64 + lane) * 8]);
    }
    __syncthreads();
    short8 eh[4], el[4], bh[4], bm[4], bl[4];
#pragma unroll
    for (int i = 0; i < 4; ++i) {
      eh[i] = *(const short8*)(sm + ((wr * 4 + i) * 64 + rI) * 8);
      el[i] = *(const short8*)(sm + (512 + (wr * 4 + i) * 64 + rI) * 8);
      bh[i] = *(const short8*)(sm + (1024 + (wc * 4 + i) * 64 + rI) * 8);
      bm[i] = *(const short8*)(sm + (1536 + (wc * 4 + i) * 64 + rI) * 8);
      bl[i] = *(const short8*)(sm + (2048 + (wc * 4 + i) * 64 + rI) * 8);
    }
#pragma unroll
    for (int i = 0; i < 4; ++i)
#pragma unroll
      for (int j = 0; j < 4; ++j) {
        acc[i][j] = __builtin_amdgcn_mfma_f32_16x16x32_bf16(eh[i], bh[j], acc[i][j], 0, 0, 0);
        acc[i][j] = __builtin_amdgcn_mfma_f32_16x16x32_bf16(eh[i], bm[j], acc[i][j], 0, 0, 0);
        acc[i][j] = __builtin_amdgcn_mfma_f32_16x16x32_bf16(eh[i], bl[j], acc[i][j], 0, 0, 0);
        acc[i][j] = __builtin_amdgcn_mfma_f32_16x16x32_bf16(el[i], bh[j], acc[i][j], 0, 0, 0);
        acc[i][j] = __builtin_amdgcn_mfma_f32_16x16x32_bf16(el[i], bm[j], acc[i][j], 0, 0, 0);
      }
  }

  // fused per-row argmax over this wave's 64 cols (tie-break: min global idx)
  const int cc = lane & 15;
  const int mtile = blockIdx.x * 2 + wc;              // [0,16)
#pragma unroll
  for (int i = 0; i < 4; ++i)
#pragma unroll
    for (int reg = 0; reg < 4; ++reg) {
      float bv = acc[i][0][reg];
      int bi = m0 + wc * 64 + cc;
#pragma unroll
      for (int j = 1; j < 4; ++j) {
        const float v = acc[i][j][reg];
        if (v > bv) { bv = v; bi = m0 + wc * 64 + j * 16 + cc; }
      }
#pragma unroll
      for (int msk = 8; msk; msk >>= 1) {
        const float ov = __shfl_xor(bv, msk);
        const int   oi = __shfl_xor(bi, msk);
        if (ov > bv || (ov == bv && oi < bi)) { bv = ov; bi = oi; }
      }
      if (cc == 0) {
        const int row = gm + wr * 64 + i * 16 + ((lane >> 4) << 2) + reg;
        PV[row * 16 + mtile] = bv;
        PI[row * 16 + mtile] = bi;
      }
    }
}

// ---------------------------------------------------------------------------
// K6: per row: reduce 16 partials, KL = self - best, gather Q. Wave per row.
// ---------------------------------------------------------------------------
__global__ __launch_bounds__(256) void k_scan(const float* __restrict__ PV,
                                              const int* __restrict__ PI,
                                              const float* __restrict__ SELF,
                                              const float* __restrict__ E,
                                              float* __restrict__ Q,
                                              float* __restrict__ KL) {
  const int tid = threadIdx.x;
  const int lane = tid & 63;
  const int row = blockIdx.x * 4 + (tid >> 6);

  float bv = -1e30f;
  int bi = 0x7fffffff;
  if (lane < 16) { bv = PV[row * 16 + lane]; bi = PI[row * 16 + lane]; }
#pragma unroll
  for (int m = 32; m; m >>= 1) {
    const float ov = __shfl_xor(bv, m);
    const int   oi = __shfl_xor(bi, m);
    if (ov > bv || (ov == bv && oi < bi)) { bv = ov; bi = oi; }
  }
  if (lane == 0) KL[row] = SELF[row] - bv;
  float4 e4 = *(const float4*)&E[((size_t)bi << 8) + lane * 4];
  *(float4*)&Q[((size_t)row << 8) + lane * 4] = e4;
}

// ---------------------------------------------------------------------------
// K7: loss = 0.25/B * sum_n kl[n]*mask[n]
// ---------------------------------------------------------------------------
__global__ __launch_bounds__(256) void k_loss(const float* __restrict__ KL,
                                              const float* __restrict__ MASK,
                                              float* __restrict__ out) {
  __shared__ float red[4];
  const int tid = threadIdx.x;
  float s = 0.f;
  for (int i = tid; i < NROWS; i += 256) s += KL[i] * MASK[i];
#pragma unroll
  for (int m = 32; m; m >>= 1) s += __shfl_xor(s, m);
  if ((tid & 63) == 0) red[tid >> 6] = s;
  __syncthreads();
  if (tid == 0) out[0] = (red[0] + red[1] + red[2] + red[3]) * (0.25f / 16.f);
}

// ---------------------------------------------------------------------------
extern "C" void kernel_launch(void* const* d_in, const int* in_sizes, int n_in,
                              void* d_out, int out_size, void* d_ws, size_t ws_size,
                              hipStream_t stream) {
  const float* x     = (const float*)d_in[0];
  const float* masks = (const float*)d_in[1];
  const float* W1    = (const float*)d_in[2];
  const float* ln_g  = (const float*)d_in[3];
  const float* ln_b  = (const float*)d_in[4];
  const float* W2    = (const float*)d_in[5];
  const float* b2    = (const float*)d_in[6];
  const float* emb   = (const float*)d_in[7];

  float* z_out = (float*)d_out;
  float* q_out = z_out + (size_t)NROWS * DD;
  float* loss_out = z_out + 2 * (size_t)NROWS * DD;

  char* ws = (char*)d_ws;
  u16*   Hh   = (u16*)(ws);                    //  67,108,864 (16384x2048)
  u16*   Hl   = (u16*)(ws + 67108864);         //  67,108,864
  u16*   W1ht = (u16*)(ws + 134217728);        //   2,097,152
  u16*   W1lt = (u16*)(ws + 136314880);        //   2,097,152
  u16*   W2ht = (u16*)(ws + 138412032);        //   1,048,576
  u16*   W2lt = (u16*)(ws + 139460608);        //   1,048,576
  u16*   LEh  = (u16*)(ws + 140509184);        //     524,288
  u16*   LEm  = (u16*)(ws + 141033472);        //     524,288
  u16*   LEl  = (u16*)(ws + 141557760);        //     524,288
  float* SELF = (float*)(ws + 142082048);      //      65,536
  float* KL   = (float*)(ws + 142147584);      //      65,536
  u16*   Xh   = (u16*)(ws + 142213120);        //   4,194,304 (quarter 4096x512)
  u16*   Xl   = (u16*)(ws + 146407424);        //   4,194,304 -> end 150,601,728
  // overlays:
  float* PV   = (float*)(ws);                  //   1,048,576 (over Hh; H dead after gemm2)
  int*   PI   = (int*)(ws + 1048576);          //   1,048,576
  u16*   EXh  = (u16*)q_out;                   //   8,388,608 (q_out dead until k_scan)
  u16*   EXl  = EXh + (size_t)NROWS * DD;      //   8,388,608

  k_split_wT<<<dim3(64, 16), 256, 0, stream>>>(W1, W1ht, W1lt, INCH, CH);
  k_split_wT<<<dim3(8, 64), 256, 0, stream>>>(W2, W2ht, W2lt, CH, DD);
  k_prep_le<<<256, 256, 0, stream>>>(emb, LEh, LEm, LEl);

  for (int q = 0; q < 4; ++q) {
    const size_t xo = (size_t)q * QROWS * INCH;
    const size_t ho = (size_t)q * QROWS * CH;
    k_split_x<<<1024, 256, 0, stream>>>(x + xo, Xh, Xl);
    k_gemm1<<<dim3(16, 32), 256, 0, stream>>>(Xh, Xl, W1ht, W1lt, Hh + ho, Hl + ho);
  }
  k_ln<<<NROWS, 256, 0, stream>>>(Hh, Hl, ln_g, ln_b);
  k_gemm2<<<NROWS / 64, 512, 0, stream>>>(Hh, Hl, W2ht, W2lt, b2, z_out, EXh, EXl, SELF);

  k_dots<<<dim3(8, 128), 256, 0, stream>>>(EXh, EXl, LEh, LEm, LEl, PV, PI);
  k_scan<<<4096, 256, 0, stream>>>(PV, PI, SELF, emb, q_out, KL);
  k_loss<<<1, 256, 0, stream>>>(KL, masks, loss_out);
}